// Round 1
// baseline (426.754 us; speedup 1.0000x reference)
//
#include <hip/hip_runtime.h>

#define Bn 4
#define Cn 32
#define Hn 720
#define Wn 720
#define W4 (Wn / 4)              // 180
#define NV (Bn * Hn * W4)        // 518,400 float4-threads

// zero-padded channel-sum buffer: 5-row halo top/bottom, 4-col halo left/right
#define PH (Hn + 10)             // 730
#define PW (Wn + 8)              // 728
#define PW4 (PW / 4)             // 182
#define SPAD_ELEMS (Bn * PH * PW)

// halo float4 bookkeeping: 10 full pad rows + 2 side float4s per data row
#define HALO_ROWS_V4 (10 * PW4)                    // 1820
#define HALO_SIDE_V4 (Hn * 2)                      // 1440
#define HALO_PER_B   (HALO_ROWS_V4 + HALO_SIDE_V4) // 3260
#define HALO_V4      (Bn * HALO_PER_B)             // 13,040

typedef float v4 __attribute__((ext_vector_type(4)));

// K1: sp[b, 5+h, 4+w] = sum_c x[b,c,h,w]   (padded layout)
// Extra tail blocks zero exactly the halo float4s (replaces full-buffer memset;
// workspace is poisoned 0xAA each call, so halo MUST be re-zeroed every launch).
__global__ void csum_kernel(const float* __restrict__ x,
                            float* __restrict__ sp) {
    int idx = blockIdx.x * blockDim.x + threadIdx.x;
    if (idx < NV) {
        int b = idx / (Hn * W4);
        int rem = idx - b * (Hn * W4);
        int h = rem / W4;
        int w4 = rem - h * W4;
        const v4* xp = (const v4*)x + (size_t)b * Cn * Hn * W4 + rem;
        v4 acc = {0.f, 0.f, 0.f, 0.f};
        #pragma unroll 8
        for (int c = 0; c < Cn; ++c) {
            v4 v = __builtin_nontemporal_load(&xp[(size_t)c * Hn * W4]);
            acc += v;
        }
        // data col 4+4*w4 -> float4 index 1+w4 (halo col-pad keeps 16B alignment)
        v4* dst = (v4*)sp + ((size_t)b * PH + 5 + h) * PW4 + 1 + w4;
        *dst = acc;
    } else {
        int hv = idx - NV;
        if (hv < HALO_V4) {
            int b = hv / HALO_PER_B;
            int r = hv - b * HALO_PER_B;
            int pr, c4;
            if (r < HALO_ROWS_V4) {              // 5 top + 5 bottom full pad rows
                int ri = r / PW4;
                c4 = r - ri * PW4;
                pr = (ri < 5) ? ri : (Hn + ri);  // rows 0..4 and 725..729
            } else {                             // left/right 4-col pads per data row
                int rr = r - HALO_ROWS_V4;
                pr = 5 + (rr >> 1);
                c4 = (rr & 1) ? (PW4 - 1) : 0;   // float4 0 (cols 0-3) / 181 (cols 724-727)
            }
            v4 z = {0.f, 0.f, 0.f, 0.f};
            ((v4*)sp)[((size_t)b * PH + pr) * PW4 + c4] = z;
        }
    }
}

// K2: fused wsum + diag-pool + 3x1 conv.
// ws[o*3+kh] = sum_i conv_w[o,i,kh,0]   (recomputed per block from L2-cached 12KB)
// d[r] = (1/9) * sum_{t=-4..4} s[r+t, w+t];  out[o,h] = sum_j ws[o,j]*d[h-1+j]
__global__ void fused_kernel(const float* __restrict__ sp,
                             const float* __restrict__ conv_w,
                             float* __restrict__ out) {
    __shared__ float ws[96];
    if (threadIdx.x < 96) {
        int o = threadIdx.x / 3, kh = threadIdx.x - o * 3;
        float acc = 0.f;
        #pragma unroll
        for (int i = 0; i < Cn; ++i)
            acc += conv_w[(o * Cn + i) * 3 + kh];
        ws[threadIdx.x] = acc;
    }
    __syncthreads();
    int idx = blockIdx.x * blockDim.x + threadIdx.x;
    if (idx >= NV) return;
    int b = idx / (Hn * W4);
    int rem = idx - b * (Hn * W4);
    int h = rem / W4;
    int w4 = rem - h * W4;
    // center pointer at padded (row 5+h, col 4 + 4*w4)
    const float* srow = sp + ((size_t)b * PH + 5 + h) * PW + 4 + 4 * w4;

    float a0[4] = {0,0,0,0}, a1[4] = {0,0,0,0}, a2[4] = {0,0,0,0};
    #pragma unroll
    for (int r = -5; r <= 5; ++r) {
        const float* p = srow + (long)r * PW - 4;   // padded col (w0-4), 16B aligned
        v4 u0 = *(const v4*)p;
        v4 u1 = *(const v4*)(p + 4);
        v4 u2 = *(const v4*)(p + 8);
        float v[12] = {u0[0],u0[1],u0[2],u0[3],
                       u1[0],u1[1],u1[2],u1[3],
                       u2[0],u2[1],u2[2],u2[3]};
        #pragma unroll
        for (int j = 0; j < 3; ++j) {
            const int t = r + 1 - j;                // tap index for d-row h-1+j
            if (t >= -4 && t <= 4) {
                float* a = (j == 0) ? a0 : (j == 1) ? a1 : a2;
                #pragma unroll
                for (int l = 0; l < 4; ++l) a[l] += v[4 + l + t];
            }
        }
    }
    // conv zero-padding in h: d[-1] and d[720] are exactly zero
    if (h == 0)      { a0[0]=a0[1]=a0[2]=a0[3]=0.f; }
    if (h == Hn - 1) { a2[0]=a2[1]=a2[2]=a2[3]=0.f; }

    const float inv9 = 1.f / 9.f;
    float* ob = out + (size_t)b * Cn * Hn * Wn + (size_t)h * Wn + 4 * w4;
    #pragma unroll
    for (int o = 0; o < Cn; ++o) {
        float k0 = ws[3*o] * inv9, k1 = ws[3*o+1] * inv9, k2 = ws[3*o+2] * inv9;
        v4 r;
        #pragma unroll
        for (int l = 0; l < 4; ++l)
            r[l] = k0 * a0[l] + k1 * a1[l] + k2 * a2[l];
        __builtin_nontemporal_store(r, (v4*)(ob + (size_t)o * Hn * Wn));
    }
}

extern "C" void kernel_launch(void* const* d_in, const int* in_sizes, int n_in,
                              void* d_out, int out_size, void* d_ws, size_t ws_size,
                              hipStream_t stream) {
    const float* x = (const float*)d_in[0];
    const float* conv_w = (const float*)d_in[1];
    float* out = (float*)d_out;
    float* sp = (float*)d_ws;               // SPAD_ELEMS floats (~8.5 MB)

    const int threads = 256;
    const int csum_blocks  = (NV + HALO_V4 + threads - 1) / threads;  // 2076
    const int fused_blocks = (NV + threads - 1) / threads;            // 2025

    csum_kernel <<<csum_blocks,  threads, 0, stream>>>(x, sp);
    fused_kernel<<<fused_blocks, threads, 0, stream>>>(sp, conv_w, out);
}